// Round 1
// baseline (8725.759 us; speedup 1.0000x reference)
//
#include <hip/hip_runtime.h>

// ---------------------------------------------------------------------------
// TLSTM  (B=256, T=256, D=256, H=512)
// Persistent-scan design:
//   grid = 256 WGs x 256 thr (1 WG/CU, LDS-limited). WG (g,cs): g=bid&7 owns
//   batch rows [g*32,+32), cs=bid>>3 owns h-cols [cs*16,+16).
//   Per step: stage h/c/x rows into LDS, 5 GEMM tiles via bf16 MFMA
//   (U/Wd B-fragments register-resident, Win in LDS), elementwise gate math in
//   fp32 (cell master state in 2 regs/thread), publish h/c bf16, group-local
//   flag barrier (agent scope, placement-independent correctness).
// ---------------------------------------------------------------------------

#define T_STEPS 256
#define BATCH   256
#define DIN     256
#define HID     512

typedef __attribute__((ext_vector_type(8))) __bf16 bf16x8;
typedef __attribute__((ext_vector_type(4))) float  f32x4;

#define MFMA(a,b,c) __builtin_amdgcn_mfma_f32_16x16x32_bf16((a),(b),(c),0,0,0)

// LDS layout (byte offsets). Row pads (+8 bf16) break power-of-2 bank strides.
#define H_S     0            // 32 x 1040B (520 bf16)
#define C_S     33280        // 32 x 1040B
#define X_S     66560        // 32 x 528B  (264 bf16)
#define WIN_S   83456        // 4 x 16 x 528B
#define Z_S     117248       // 18 tiles x 16x17 f32
#define LDS_SZ  136832
#define HSTR    1040
#define XSTR    528
#define ZROW    17

struct ScanP {
  const float *x, *tim;
  const float *Wi_w,*Wi_b,*Ui_w,*Ui_b,*bi;
  const float *Wf_w,*Wf_b,*Uf_w,*Uf_b,*bf_;
  const float *Wo_w,*Wo_b,*Uo_w,*Uo_b,*bo;
  const float *Wc_w,*Wc_b,*Uc_w,*Uc_b,*bc;
  const float *Wd_w,*b_dec;
  unsigned short *h_buf, *c_buf;   // bf16 bits, [2][256][512] double-buffered
  float *h_final;                  // [256][512] fp32
  unsigned int *flags;             // [8][32]
};

__device__ __forceinline__ float fsigm(float z){ return 1.f/(1.f + __expf(-z)); }
__device__ __forceinline__ float ftanh(float z){
  float e = __expf(-2.f*fabsf(z));
  float t = (1.f - e)/(1.f + e);
  return z < 0.f ? -t : t;
}
__device__ __forceinline__ bf16x8 wfrag8(const float* p){
  const float4* p4 = (const float4*)p;
  float4 a = p4[0], b = p4[1];
  bf16x8 r = { (__bf16)a.x,(__bf16)a.y,(__bf16)a.z,(__bf16)a.w,
               (__bf16)b.x,(__bf16)b.y,(__bf16)b.z,(__bf16)b.w };
  return r;
}
__device__ __forceinline__ void zstore(char* L, int tile, int lane, f32x4 v){
  float* p = (float*)(L + Z_S) + tile*(16*ZROW) + ((lane>>4)*4)*ZROW + (lane&15);
  p[0]=v[0]; p[ZROW]=v[1]; p[2*ZROW]=v[2]; p[3*ZROW]=v[3];
}
__device__ __forceinline__ float zread(const char* L, int tile, int r, int c){
  return ((const float*)(L + Z_S))[tile*(16*ZROW) + r*ZROW + c];
}

// Z tile ids: gate g U-part = g*2+m ; x-part = 8+4*m+g ; decomp = 16+m
__global__ void __launch_bounds__(256, 1) tlstm_scan(ScanP P)
{
  __shared__ __align__(16) char L[LDS_SZ];
  const int tid  = threadIdx.x;
  const int bid  = blockIdx.x;
  const int g    = bid & 7;          // row group (XCD-locality heuristic only)
  const int cs   = bid >> 3;         // 0..31
  const int rbase = g * 32;
  const int cbase = cs * 16;
  const int wave = tid >> 6, lane = tid & 63, lo = lane & 15, hi = lane >> 4;

  // ---- one-time: Win slices (4 gates x 16 cols x 256) fp32 -> bf16 -> LDS
  {
    const float* Wg = (tid < 64) ? P.Wi_w : (tid < 128) ? P.Wf_w
                    : (tid < 192) ? P.Wo_w : P.Wc_w;
    int wr = (tid >> 2) & 15, q = tid & 3;
    const float4* src = (const float4*)(Wg + (size_t)(cbase + wr) * DIN + q * 64);
    char* dst = L + WIN_S + (size_t)((tid >> 6) * 16 + wr) * XSTR + q * 128;
#pragma unroll
    for (int j = 0; j < 8; j++){
      float4 a = src[2*j], b = src[2*j+1];
      bf16x8 o = { (__bf16)a.x,(__bf16)a.y,(__bf16)a.z,(__bf16)a.w,
                   (__bf16)b.x,(__bf16)b.y,(__bf16)b.z,(__bf16)b.w };
      *(bf16x8*)(dst + j*16) = o;
    }
  }

  // ---- one-time: U/Wd B-fragments -> registers (loop-invariant, ~128 VGPR)
  bf16x8 bP[16], bQ[16];
  {
    const float* Pw = (wave == 0) ? P.Ui_w : (wave == 1) ? P.Uo_w : P.Wd_w;
#pragma unroll
    for (int kc = 0; kc < 16; kc++)
      bP[kc] = wfrag8(Pw + (size_t)(cbase + lo) * HID + kc * 32 + hi * 8);
    if (wave < 2){
      const float* Qw = (wave == 0) ? P.Uf_w : P.Uc_w;
#pragma unroll
      for (int kc = 0; kc < 16; kc++)
        bQ[kc] = wfrag8(Qw + (size_t)(cbase + lo) * HID + kc * 32 + hi * 8);
    }
  }

  // ---- per-thread elementwise ownership: row=tid>>3, cols cbase+(tid&7)*2..+1
  const int erow = tid >> 3;
  const int ecp  = (tid & 7) * 2;
  float bias_i[2], bias_f[2], bias_o[2], bias_c[2], bias_d[2], cr[2];
#pragma unroll
  for (int e = 0; e < 2; e++){
    int c = cbase + ecp + e;
    bias_i[e] = P.Wi_b[c] + P.bi[c]  + P.Ui_b[c];
    bias_f[e] = P.Wf_b[c] + P.bf_[c] + P.Uf_b[c];
    bias_o[e] = P.Wo_b[c] + P.bo[c]  + P.Uo_b[c];
    bias_c[e] = P.Wc_b[c] + P.bc[c]  + P.Uc_b[c];
    bias_d[e] = P.b_dec[c];
    cr[e] = 0.f;
  }

  unsigned int* gflags = P.flags + g * 32;
  const int member = cs;
  const int srow = tid >> 3, sseg = tid & 7;   // staging map

#pragma unroll 1
  for (int t = 0; t < T_STEPS; ++t){
    const int rp = t & 1;
    const unsigned short* hprev = P.h_buf + (size_t)rp * BATCH * HID;
    const unsigned short* cprev = P.c_buf + (size_t)rp * BATCH * HID;
    unsigned short* hnext = P.h_buf + (size_t)(rp ^ 1) * BATCH * HID;
    unsigned short* cnext = P.c_buf + (size_t)(rp ^ 1) * BATCH * HID;

    // x slice does not depend on peers: issue its global loads before polling
    const float4* xsrc = (const float4*)(P.x + ((size_t)(rbase + srow) * T_STEPS + t) * DIN + sseg * 32);
    float4 xv[8];
#pragma unroll
    for (int j = 0; j < 8; j++) xv[j] = xsrc[j];

    // ---- group barrier: wait until all 32 peers finished step t-1
    {
      bool done = false;
      while (!done){
        unsigned int v = 0xFFFFFFFFu;
        if (lane < 32)
          v = __hip_atomic_load(gflags + lane, __ATOMIC_RELAXED, __HIP_MEMORY_SCOPE_AGENT);
        done = (bool)__all((int)(lane >= 32 || v >= (unsigned int)t));
        if (!done) __builtin_amdgcn_s_sleep(2);
      }
    }
    __threadfence();      // acquire: make peers' h/c stores visible
    __syncthreads();      // also: everyone past old LDS uses -> safe to restage

    // ---- stage x (fp32 -> bf16)
    {
      char* dst = L + X_S + srow * XSTR + sseg * 64;
#pragma unroll
      for (int j = 0; j < 4; j++){
        float4 a = xv[2*j], b = xv[2*j+1];
        bf16x8 o = { (__bf16)a.x,(__bf16)a.y,(__bf16)a.z,(__bf16)a.w,
                     (__bf16)b.x,(__bf16)b.y,(__bf16)b.z,(__bf16)b.w };
        *(bf16x8*)(dst + j*16) = o;
      }
    }
    // ---- stage h, c (bf16 raw copy, 128B/thread each)
    {
      const uint4* hsrc = (const uint4*)(hprev + (size_t)(rbase + srow) * HID + sseg * 64);
      uint4* hdst = (uint4*)(L + H_S + srow * HSTR + sseg * 128);
#pragma unroll
      for (int j = 0; j < 8; j++) hdst[j] = hsrc[j];
      const uint4* csrc = (const uint4*)(cprev + (size_t)(rbase + srow) * HID + sseg * 64);
      uint4* cdst = (uint4*)(L + C_S + srow * HSTR + sseg * 128);
#pragma unroll
      for (int j = 0; j < 8; j++) cdst[j] = csrc[j];
    }
    __syncthreads();

    // ---- MFMA phase
    if (wave < 2){
      // wave0: Zi,Zf (U-parts, both M-tiles); wave1: Zo,Zc
      f32x4 z0 = {0.f,0.f,0.f,0.f}, z1 = z0, z2 = z0, z3 = z0;
#pragma unroll
      for (int kc = 0; kc < 16; kc++){
        bf16x8 a0 = *(const bf16x8*)(L + H_S + lo * HSTR        + kc*64 + hi*16);
        bf16x8 a1 = *(const bf16x8*)(L + H_S + (16 + lo) * HSTR + kc*64 + hi*16);
        z0 = MFMA(a0, bP[kc], z0);
        z1 = MFMA(a1, bP[kc], z1);
        z2 = MFMA(a0, bQ[kc], z2);
        z3 = MFMA(a1, bQ[kc], z3);
      }
      int tb = wave * 4;   // tiles {0..3} = Zi m0,m1, Zf m0,m1 ; {4..7} = Zo,Zc
      zstore(L, tb+0, lane, z0); zstore(L, tb+1, lane, z1);
      zstore(L, tb+2, lane, z2); zstore(L, tb+3, lane, z3);
    } else {
      // wave2: x-projections m0 (4 gates) + decomp m0 ; wave3: same for m1
      const int m = wave - 2;
      f32x4 xi = {0.f,0.f,0.f,0.f}, xf = xi, xo = xi, xcg = xi, zd = xi;
#pragma unroll
      for (int q = 0; q < 8; q++){
        bf16x8 a  = *(const bf16x8*)(L + X_S   + (m*16 + lo) * XSTR + q*64 + hi*16);
        bf16x8 w0 = *(const bf16x8*)(L + WIN_S + (0*16 + lo) * XSTR + q*64 + hi*16);
        bf16x8 w1 = *(const bf16x8*)(L + WIN_S + (1*16 + lo) * XSTR + q*64 + hi*16);
        bf16x8 w2 = *(const bf16x8*)(L + WIN_S + (2*16 + lo) * XSTR + q*64 + hi*16);
        bf16x8 w3 = *(const bf16x8*)(L + WIN_S + (3*16 + lo) * XSTR + q*64 + hi*16);
        xi  = MFMA(a, w0, xi);  xf  = MFMA(a, w1, xf);
        xo  = MFMA(a, w2, xo);  xcg = MFMA(a, w3, xcg);
      }
#pragma unroll
      for (int kc = 0; kc < 16; kc++){
        bf16x8 a = *(const bf16x8*)(L + C_S + (m*16 + lo) * HSTR + kc*64 + hi*16);
        zd = MFMA(a, bP[kc], zd);
      }
      zstore(L, 8+4*m+0, lane, xi);  zstore(L, 8+4*m+1, lane, xf);
      zstore(L, 8+4*m+2, lane, xo);  zstore(L, 8+4*m+3, lane, xcg);
      zstore(L, 16+m,    lane, zd);
    }
    __syncthreads();

    // ---- elementwise gate math (fp32), publish h/c bf16
    {
      const int m = erow >> 4, r16 = erow & 15;
      float tv   = P.tim[(size_t)(rbase + erow) * T_STEPS + t];
      float Tmap = 1.f / __logf(tv + 2.7183f);
      unsigned int hpk = 0, cpk = 0;
      float hv2[2];
#pragma unroll
      for (int e = 0; e < 2; e++){
        int col = ecp + e;
        float zi = zread(L, 0*2+m, r16, col) + zread(L, 8+4*m+0, r16, col) + bias_i[e];
        float zf = zread(L, 1*2+m, r16, col) + zread(L, 8+4*m+1, r16, col) + bias_f[e];
        float zo = zread(L, 2*2+m, r16, col) + zread(L, 8+4*m+2, r16, col) + bias_o[e];
        float zc = zread(L, 3*2+m, r16, col) + zread(L, 8+4*m+3, r16, col) + bias_c[e];
        float zdv = zread(L, 16+m, r16, col) + bias_d[e];
        float cst = ftanh(zdv);
        float c1  = cr[e] - cst + Tmap * cst;
        float ig = fsigm(zi), fg = fsigm(zf), og = fsigm(zo);
        float ch = ftanh(zc);
        float c2 = fg * c1 + ig * ch;
        float hv = og * ftanh(c2);
        cr[e] = c2; hv2[e] = hv;
        hpk |= (unsigned int)__builtin_bit_cast(unsigned short, (__bf16)hv) << (16*e);
        cpk |= (unsigned int)__builtin_bit_cast(unsigned short, (__bf16)c2) << (16*e);
      }
      size_t off = (size_t)(rbase + erow) * HID + cbase + ecp;
      *(unsigned int*)(hnext + off) = hpk;
      *(unsigned int*)(cnext + off) = cpk;
      if (t == T_STEPS - 1){
        P.h_final[off]     = hv2[0];
        P.h_final[off + 1] = hv2[1];
      }
    }
    __syncthreads();              // all stores issued + drained (barrier waitcnt)
    if (tid == 0){
      __threadfence();            // release: flush to agent coherence point
      __hip_atomic_store(gflags + member, (unsigned int)(t + 1),
                         __ATOMIC_RELEASE, __HIP_MEMORY_SCOPE_AGENT);
    }
  }
}

// ---------------- head: out = relu(hT @ fc_w^T + fc_b) @ cls_w^T + cls_b ----
__global__ void __launch_bounds__(256) tlstm_head(const float* __restrict__ hfin,
    const float* __restrict__ fc_w, const float* __restrict__ fc_b,
    const float* __restrict__ cls_w, const float* __restrict__ cls_b,
    float* __restrict__ out)
{
  __shared__ float hrow[512];
  __shared__ float fcv[256];
  const int b = blockIdx.x, tid = threadIdx.x;
  ((float2*)hrow)[tid] = ((const float2*)(hfin + (size_t)b * 512))[tid];
  __syncthreads();
  {
    const float4* w4 = (const float4*)(fc_w + (size_t)tid * 512);
    const float4* h4 = (const float4*)hrow;
    float acc = fc_b[tid];
#pragma unroll 4
    for (int k = 0; k < 128; k++){
      float4 w = w4[k], h = h4[k];
      acc += w.x*h.x + w.y*h.y + w.z*h.z + w.w*h.w;
    }
    fcv[tid] = fmaxf(acc, 0.f);
  }
  __syncthreads();
  const int wave = tid >> 6, lane = tid & 63;
  if (wave < 2){
    const float* cw = cls_w + wave * 256;
    float s = 0.f;
#pragma unroll
    for (int j = lane; j < 256; j += 64) s += fcv[j] * cw[j];
#pragma unroll
    for (int off = 32; off > 0; off >>= 1) s += __shfl_down(s, off, 64);
    if (lane == 0) out[b * 2 + wave] = s + cls_b[wave];
  }
}

// ---------------------------------------------------------------------------
extern "C" void kernel_launch(void* const* d_in, const int* in_sizes, int n_in,
                              void* d_out, int out_size, void* d_ws, size_t ws_size,
                              hipStream_t stream)
{
  (void)in_sizes; (void)n_in; (void)out_size; (void)ws_size;

  ScanP P;
  P.x    = (const float*)d_in[0];
  P.tim  = (const float*)d_in[1];
  P.Wi_w = (const float*)d_in[2];  P.Wi_b = (const float*)d_in[3];
  P.Ui_w = (const float*)d_in[4];  P.Ui_b = (const float*)d_in[5];  P.bi  = (const float*)d_in[6];
  P.Wf_w = (const float*)d_in[7];  P.Wf_b = (const float*)d_in[8];
  P.Uf_w = (const float*)d_in[9];  P.Uf_b = (const float*)d_in[10]; P.bf_ = (const float*)d_in[11];
  P.Wo_w = (const float*)d_in[12]; P.Wo_b = (const float*)d_in[13];
  P.Uo_w = (const float*)d_in[14]; P.Uo_b = (const float*)d_in[15]; P.bo  = (const float*)d_in[16];
  P.Wc_w = (const float*)d_in[17]; P.Wc_b = (const float*)d_in[18];
  P.Uc_w = (const float*)d_in[19]; P.Uc_b = (const float*)d_in[20]; P.bc  = (const float*)d_in[21];
  P.Wd_w = (const float*)d_in[22]; P.b_dec = (const float*)d_in[23];
  const float* fc_w  = (const float*)d_in[24];
  const float* fc_b  = (const float*)d_in[25];
  const float* cls_w = (const float*)d_in[26];
  const float* cls_b = (const float*)d_in[27];

  // workspace layout
  unsigned short* h_buf = (unsigned short*)d_ws;                 // 2*256*512 bf16
  unsigned short* c_buf = h_buf + 2 * BATCH * HID;               // 2*256*512 bf16
  float* h_final        = (float*)(c_buf + 2 * BATCH * HID);     // 256*512 f32
  unsigned int* flags   = (unsigned int*)(h_final + BATCH * HID);// 256 flags
  P.h_buf = h_buf; P.c_buf = c_buf; P.h_final = h_final; P.flags = flags;

  const size_t ws_used = (size_t)2 * BATCH * HID * 2 * 2   // h_buf + c_buf
                       + (size_t)BATCH * HID * 4           // h_final
                       + 1024;                             // flags
  hipMemsetAsync(d_ws, 0, ws_used, stream);                // zero h0/c0/flags

  hipLaunchKernelGGL(tlstm_scan, dim3(256), dim3(256), 0, stream, P);
  hipLaunchKernelGGL(tlstm_head, dim3(256), dim3(256), 0, stream,
                     h_final, fc_w, fc_b, cls_w, cls_b, (float*)d_out);
}

// Round 2
// 2910.771 us; speedup vs baseline: 2.9977x; 2.9977x over previous
//
#include <hip/hip_runtime.h>

// ---------------------------------------------------------------------------
// TLSTM  (B=256, T=256, D=256, H=512)
// Persistent-scan, R1: fence-free cross-WG sync.
//   grid = 256 WGs x 256 thr (1 WG/CU). WG (g,cs): g=bid&7 owns batch rows
//   [g*32,+32), cs=bid>>3 owns h-cols [cs*16,+16).
//   h/c exchanged through the MALL (Infinity Cache) via relaxed agent-scope
//   atomics (bypass non-coherent per-XCD L2). Release = per-wave
//   s_waitcnt vmcnt(0) + s_barrier, then flag store. NO __threadfence
//   (previous version's buffer_wbl2/inv per step was 97% of runtime).
// ---------------------------------------------------------------------------

#define T_STEPS 256
#define BATCH   256
#define DIN     256
#define HID     512

typedef __attribute__((ext_vector_type(8))) __bf16 bf16x8;
typedef __attribute__((ext_vector_type(4))) float  f32x4;

#define MFMA(a,b,c) __builtin_amdgcn_mfma_f32_16x16x32_bf16((a),(b),(c),0,0,0)

// LDS layout (byte offsets). Row pads (+8 bf16) break power-of-2 bank strides.
#define H_S     0            // 32 x 1040B (520 bf16)
#define C_S     33280        // 32 x 1040B
#define X_S     66560        // 32 x 528B  (264 bf16)
#define WIN_S   83456        // 4 x 16 x 528B
#define Z_S     117248       // 18 tiles x 16x17 f32
#define LDS_SZ  136832
#define HSTR    1040
#define XSTR    528
#define ZROW    17

struct ScanP {
  const float *x, *tim;
  const float *Wi_w,*Wi_b,*Ui_w,*Ui_b,*bi;
  const float *Wf_w,*Wf_b,*Uf_w,*Uf_b,*bf_;
  const float *Wo_w,*Wo_b,*Uo_w,*Uo_b,*bo;
  const float *Wc_w,*Wc_b,*Uc_w,*Uc_b,*bc;
  const float *Wd_w,*b_dec;
  unsigned short *h_buf, *c_buf;   // bf16 bits, [2][256][512] double-buffered
  float *h_final;                  // [256][512] fp32
  unsigned int *flags;             // [8][32]
};

__device__ __forceinline__ float fsigm(float z){ return 1.f/(1.f + __expf(-z)); }
__device__ __forceinline__ float ftanh(float z){
  float e = __expf(-2.f*fabsf(z));
  float t = (1.f - e)/(1.f + e);
  return z < 0.f ? -t : t;
}
// Coherence-point (MALL) accesses: relaxed agent-scope atomics bypass the
// non-coherent per-XCD L2. No fences required anywhere.
__device__ __forceinline__ unsigned long long cload_u64(const unsigned long long* p){
  return __hip_atomic_load(p, __ATOMIC_RELAXED, __HIP_MEMORY_SCOPE_AGENT);
}
__device__ __forceinline__ unsigned int cload_u32(const unsigned int* p){
  return __hip_atomic_load(p, __ATOMIC_RELAXED, __HIP_MEMORY_SCOPE_AGENT);
}
__device__ __forceinline__ void cstore_u32(unsigned int* p, unsigned int v){
  __hip_atomic_store(p, v, __ATOMIC_RELAXED, __HIP_MEMORY_SCOPE_AGENT);
}

__device__ __forceinline__ bf16x8 wfrag8(const float* p){
  const float4* p4 = (const float4*)p;
  float4 a = p4[0], b = p4[1];
  bf16x8 r = { (__bf16)a.x,(__bf16)a.y,(__bf16)a.z,(__bf16)a.w,
               (__bf16)b.x,(__bf16)b.y,(__bf16)b.z,(__bf16)b.w };
  return r;
}
__device__ __forceinline__ void zstore(char* L, int tile, int lane, f32x4 v){
  float* p = (float*)(L + Z_S) + tile*(16*ZROW) + ((lane>>4)*4)*ZROW + (lane&15);
  p[0]=v[0]; p[ZROW]=v[1]; p[2*ZROW]=v[2]; p[3*ZROW]=v[3];
}
__device__ __forceinline__ float zread(const char* L, int tile, int r, int c){
  return ((const float*)(L + Z_S))[tile*(16*ZROW) + r*ZROW + c];
}

// Z tile ids: gate g U-part = g*2+m ; x-part = 8+4*m+g ; decomp = 16+m
__global__ void __launch_bounds__(256, 1) tlstm_scan(ScanP P)
{
  __shared__ __align__(16) char L[LDS_SZ];
  const int tid  = threadIdx.x;
  const int bid  = blockIdx.x;
  const int g    = bid & 7;          // row group (XCD-locality heuristic only)
  const int cs   = bid >> 3;         // 0..31
  const int rbase = g * 32;
  const int cbase = cs * 16;
  const int wave = tid >> 6, lane = tid & 63, lo = lane & 15, hi = lane >> 4;

  // ---- one-time: Win slices (4 gates x 16 cols x 256) fp32 -> bf16 -> LDS
  {
    const float* Wg = (tid < 64) ? P.Wi_w : (tid < 128) ? P.Wf_w
                    : (tid < 192) ? P.Wo_w : P.Wc_w;
    int wr = (tid >> 2) & 15, q = tid & 3;
    const float4* src = (const float4*)(Wg + (size_t)(cbase + wr) * DIN + q * 64);
    char* dst = L + WIN_S + (size_t)((tid >> 6) * 16 + wr) * XSTR + q * 128;
#pragma unroll
    for (int j = 0; j < 8; j++){
      float4 a = src[2*j], b = src[2*j+1];
      bf16x8 o = { (__bf16)a.x,(__bf16)a.y,(__bf16)a.z,(__bf16)a.w,
                   (__bf16)b.x,(__bf16)b.y,(__bf16)b.z,(__bf16)b.w };
      *(bf16x8*)(dst + j*16) = o;
    }
  }

  // ---- one-time: U/Wd B-fragments -> registers (loop-invariant, ~128 VGPR)
  bf16x8 bP[16], bQ[16];
  {
    const float* Pw = (wave == 0) ? P.Ui_w : (wave == 1) ? P.Uo_w : P.Wd_w;
#pragma unroll
    for (int kc = 0; kc < 16; kc++)
      bP[kc] = wfrag8(Pw + (size_t)(cbase + lo) * HID + kc * 32 + hi * 8);
    if (wave < 2){
      const float* Qw = (wave == 0) ? P.Uf_w : P.Uc_w;
#pragma unroll
      for (int kc = 0; kc < 16; kc++)
        bQ[kc] = wfrag8(Qw + (size_t)(cbase + lo) * HID + kc * 32 + hi * 8);
    }
  }

  // ---- per-thread elementwise ownership: row=tid>>3, cols cbase+(tid&7)*2..+1
  const int erow = tid >> 3;
  const int ecp  = (tid & 7) * 2;
  float bias_i[2], bias_f[2], bias_o[2], bias_c[2], bias_d[2], cr[2];
#pragma unroll
  for (int e = 0; e < 2; e++){
    int c = cbase + ecp + e;
    bias_i[e] = P.Wi_b[c] + P.bi[c]  + P.Ui_b[c];
    bias_f[e] = P.Wf_b[c] + P.bf_[c] + P.Uf_b[c];
    bias_o[e] = P.Wo_b[c] + P.bo[c]  + P.Uo_b[c];
    bias_c[e] = P.Wc_b[c] + P.bc[c]  + P.Uc_b[c];
    bias_d[e] = P.b_dec[c];
    cr[e] = 0.f;
  }

  unsigned int* gflags = P.flags + g * 32;
  const int member = cs;
  const int srow = tid >> 3, sseg = tid & 7;   // staging map

#pragma unroll 1
  for (int t = 0; t < T_STEPS; ++t){
    const int rp = t & 1;
    const unsigned short* hprev = P.h_buf + (size_t)rp * BATCH * HID;
    const unsigned short* cprev = P.c_buf + (size_t)rp * BATCH * HID;
    unsigned short* hnext = P.h_buf + (size_t)(rp ^ 1) * BATCH * HID;
    unsigned short* cnext = P.c_buf + (size_t)(rp ^ 1) * BATCH * HID;

    // x slice does not depend on peers: issue its global loads before polling
    const float4* xsrc = (const float4*)(P.x + ((size_t)(rbase + srow) * T_STEPS + t) * DIN + sseg * 32);
    float4 xv[8];
#pragma unroll
    for (int j = 0; j < 8; j++) xv[j] = xsrc[j];

    // ---- group barrier: wave 0 polls until all 32 peers finished step t-1
    if (wave == 0){
      bool done = false;
      while (!done){
        unsigned int v = 0xFFFFFFFFu;
        if (lane < 32) v = cload_u32(gflags + lane);
        done = (bool)__all((int)(lane >= 32 || v >= (unsigned int)t));
        if (!done) __builtin_amdgcn_s_sleep(4);
      }
    }
    __syncthreads();      // releases waves 1-3; also: old LDS uses finished

    // ---- stage x (fp32 -> bf16)
    {
      char* dst = L + X_S + srow * XSTR + sseg * 64;
#pragma unroll
      for (int j = 0; j < 4; j++){
        float4 a = xv[2*j], b = xv[2*j+1];
        bf16x8 o = { (__bf16)a.x,(__bf16)a.y,(__bf16)a.z,(__bf16)a.w,
                     (__bf16)b.x,(__bf16)b.y,(__bf16)b.z,(__bf16)b.w };
        *(bf16x8*)(dst + j*16) = o;
      }
    }
    // ---- stage h, c via MALL (coherent u64 loads), 128B/thread each
    {
      const unsigned long long* hs = (const unsigned long long*)(hprev + (size_t)(rbase + srow) * HID + sseg * 64);
      unsigned long long* hd = (unsigned long long*)(L + H_S + srow * HSTR + sseg * 128);
      const unsigned long long* csrc = (const unsigned long long*)(cprev + (size_t)(rbase + srow) * HID + sseg * 64);
      unsigned long long* cd = (unsigned long long*)(L + C_S + srow * HSTR + sseg * 128);
#pragma unroll
      for (int j = 0; j < 16; j++) hd[j] = cload_u64(hs + j);
#pragma unroll
      for (int j = 0; j < 16; j++) cd[j] = cload_u64(csrc + j);
    }
    __syncthreads();

    // ---- MFMA phase
    if (wave < 2){
      // wave0: Zi,Zf (U-parts, both M-tiles); wave1: Zo,Zc
      f32x4 z0 = {0.f,0.f,0.f,0.f}, z1 = z0, z2 = z0, z3 = z0;
#pragma unroll
      for (int kc = 0; kc < 16; kc++){
        bf16x8 a0 = *(const bf16x8*)(L + H_S + lo * HSTR        + kc*64 + hi*16);
        bf16x8 a1 = *(const bf16x8*)(L + H_S + (16 + lo) * HSTR + kc*64 + hi*16);
        z0 = MFMA(a0, bP[kc], z0);
        z1 = MFMA(a1, bP[kc], z1);
        z2 = MFMA(a0, bQ[kc], z2);
        z3 = MFMA(a1, bQ[kc], z3);
      }
      int tb = wave * 4;   // tiles {0..3} = Zi m0,m1, Zf m0,m1 ; {4..7} = Zo,Zc
      zstore(L, tb+0, lane, z0); zstore(L, tb+1, lane, z1);
      zstore(L, tb+2, lane, z2); zstore(L, tb+3, lane, z3);
    } else {
      // wave2: x-projections m0 (4 gates) + decomp m0 ; wave3: same for m1
      const int m = wave - 2;
      f32x4 xi = {0.f,0.f,0.f,0.f}, xf = xi, xo = xi, xcg = xi, zd = xi;
#pragma unroll
      for (int q = 0; q < 8; q++){
        bf16x8 a  = *(const bf16x8*)(L + X_S   + (m*16 + lo) * XSTR + q*64 + hi*16);
        bf16x8 w0 = *(const bf16x8*)(L + WIN_S + (0*16 + lo) * XSTR + q*64 + hi*16);
        bf16x8 w1 = *(const bf16x8*)(L + WIN_S + (1*16 + lo) * XSTR + q*64 + hi*16);
        bf16x8 w2 = *(const bf16x8*)(L + WIN_S + (2*16 + lo) * XSTR + q*64 + hi*16);
        bf16x8 w3 = *(const bf16x8*)(L + WIN_S + (3*16 + lo) * XSTR + q*64 + hi*16);
        xi  = MFMA(a, w0, xi);  xf  = MFMA(a, w1, xf);
        xo  = MFMA(a, w2, xo);  xcg = MFMA(a, w3, xcg);
      }
#pragma unroll
      for (int kc = 0; kc < 16; kc++){
        bf16x8 a = *(const bf16x8*)(L + C_S + (m*16 + lo) * HSTR + kc*64 + hi*16);
        zd = MFMA(a, bP[kc], zd);
      }
      zstore(L, 8+4*m+0, lane, xi);  zstore(L, 8+4*m+1, lane, xf);
      zstore(L, 8+4*m+2, lane, xo);  zstore(L, 8+4*m+3, lane, xcg);
      zstore(L, 16+m,    lane, zd);
    }
    __syncthreads();

    // ---- elementwise gate math (fp32), publish h/c bf16 via MALL
    {
      const int m = erow >> 4, r16 = erow & 15;
      float tv   = P.tim[(size_t)(rbase + erow) * T_STEPS + t];
      float Tmap = 1.f / __logf(tv + 2.7183f);
      unsigned int hpk = 0, cpk = 0;
      float hv2[2];
#pragma unroll
      for (int e = 0; e < 2; e++){
        int col = ecp + e;
        float zi = zread(L, 0*2+m, r16, col) + zread(L, 8+4*m+0, r16, col) + bias_i[e];
        float zf = zread(L, 1*2+m, r16, col) + zread(L, 8+4*m+1, r16, col) + bias_f[e];
        float zo = zread(L, 2*2+m, r16, col) + zread(L, 8+4*m+2, r16, col) + bias_o[e];
        float zc = zread(L, 3*2+m, r16, col) + zread(L, 8+4*m+3, r16, col) + bias_c[e];
        float zdv = zread(L, 16+m, r16, col) + bias_d[e];
        float cst = ftanh(zdv);
        float c1  = cr[e] - cst + Tmap * cst;
        float ig = fsigm(zi), fg = fsigm(zf), og = fsigm(zo);
        float ch = ftanh(zc);
        float c2 = fg * c1 + ig * ch;
        float hv = og * ftanh(c2);
        cr[e] = c2; hv2[e] = hv;
        hpk |= (unsigned int)__builtin_bit_cast(unsigned short, (__bf16)hv) << (16*e);
        cpk |= (unsigned int)__builtin_bit_cast(unsigned short, (__bf16)c2) << (16*e);
      }
      size_t off = (size_t)(rbase + erow) * HID + cbase + ecp;
      cstore_u32((unsigned int*)(hnext + off), hpk);
      cstore_u32((unsigned int*)(cnext + off), cpk);
      if (t == T_STEPS - 1){
        P.h_final[off]     = hv2[0];
        P.h_final[off + 1] = hv2[1];
      }
    }
    // release: each wave drains its own (MALL-acked) stores, then barrier,
    // then the flag store — data is globally visible before the flag issues.
    asm volatile("s_waitcnt vmcnt(0)" ::: "memory");
    __syncthreads();
    if (tid == 0) cstore_u32(gflags + member, (unsigned int)(t + 1));
  }
}

// ---------------- head: out = relu(hT @ fc_w^T + fc_b) @ cls_w^T + cls_b ----
__global__ void __launch_bounds__(256) tlstm_head(const float* __restrict__ hfin,
    const float* __restrict__ fc_w, const float* __restrict__ fc_b,
    const float* __restrict__ cls_w, const float* __restrict__ cls_b,
    float* __restrict__ out)
{
  __shared__ float hrow[512];
  __shared__ float fcv[256];
  const int b = blockIdx.x, tid = threadIdx.x;
  ((float2*)hrow)[tid] = ((const float2*)(hfin + (size_t)b * 512))[tid];
  __syncthreads();
  {
    const float4* w4 = (const float4*)(fc_w + (size_t)tid * 512);
    const float4* h4 = (const float4*)hrow;
    float acc = fc_b[tid];
#pragma unroll 4
    for (int k = 0; k < 128; k++){
      float4 w = w4[k], h = h4[k];
      acc += w.x*h.x + w.y*h.y + w.z*h.z + w.w*h.w;
    }
    fcv[tid] = fmaxf(acc, 0.f);
  }
  __syncthreads();
  const int wave = tid >> 6, lane = tid & 63;
  if (wave < 2){
    const float* cw = cls_w + wave * 256;
    float s = 0.f;
#pragma unroll
    for (int j = lane; j < 256; j += 64) s += fcv[j] * cw[j];
#pragma unroll
    for (int off = 32; off > 0; off >>= 1) s += __shfl_down(s, off, 64);
    if (lane == 0) out[b * 2 + wave] = s + cls_b[wave];
  }
}

// ---------------------------------------------------------------------------
extern "C" void kernel_launch(void* const* d_in, const int* in_sizes, int n_in,
                              void* d_out, int out_size, void* d_ws, size_t ws_size,
                              hipStream_t stream)
{
  (void)in_sizes; (void)n_in; (void)out_size; (void)ws_size;

  ScanP P;
  P.x    = (const float*)d_in[0];
  P.tim  = (const float*)d_in[1];
  P.Wi_w = (const float*)d_in[2];  P.Wi_b = (const float*)d_in[3];
  P.Ui_w = (const float*)d_in[4];  P.Ui_b = (const float*)d_in[5];  P.bi  = (const float*)d_in[6];
  P.Wf_w = (const float*)d_in[7];  P.Wf_b = (const float*)d_in[8];
  P.Uf_w = (const float*)d_in[9];  P.Uf_b = (const float*)d_in[10]; P.bf_ = (const float*)d_in[11];
  P.Wo_w = (const float*)d_in[12]; P.Wo_b = (const float*)d_in[13];
  P.Uo_w = (const float*)d_in[14]; P.Uo_b = (const float*)d_in[15]; P.bo  = (const float*)d_in[16];
  P.Wc_w = (const float*)d_in[17]; P.Wc_b = (const float*)d_in[18];
  P.Uc_w = (const float*)d_in[19]; P.Uc_b = (const float*)d_in[20]; P.bc  = (const float*)d_in[21];
  P.Wd_w = (const float*)d_in[22]; P.b_dec = (const float*)d_in[23];
  const float* fc_w  = (const float*)d_in[24];
  const float* fc_b  = (const float*)d_in[25];
  const float* cls_w = (const float*)d_in[26];
  const float* cls_b = (const float*)d_in[27];

  // workspace layout
  unsigned short* h_buf = (unsigned short*)d_ws;                 // 2*256*512 bf16
  unsigned short* c_buf = h_buf + 2 * BATCH * HID;               // 2*256*512 bf16
  float* h_final        = (float*)(c_buf + 2 * BATCH * HID);     // 256*512 f32
  unsigned int* flags   = (unsigned int*)(h_final + BATCH * HID);// 256 flags
  P.h_buf = h_buf; P.c_buf = c_buf; P.h_final = h_final; P.flags = flags;

  const size_t ws_used = (size_t)2 * BATCH * HID * 2 * 2   // h_buf + c_buf
                       + (size_t)BATCH * HID * 4           // h_final
                       + 1024;                             // flags
  hipMemsetAsync(d_ws, 0, ws_used, stream);                // zero h0/c0/flags

  hipLaunchKernelGGL(tlstm_scan, dim3(256), dim3(256), 0, stream, P);
  hipLaunchKernelGGL(tlstm_head, dim3(256), dim3(256), 0, stream,
                     h_final, fc_w, fc_b, cls_w, cls_b, (float*)d_out);
}

// Round 3
// 2832.090 us; speedup vs baseline: 3.0810x; 1.0278x over previous
//
#include <hip/hip_runtime.h>

// ---------------------------------------------------------------------------
// TLSTM  (B=256, T=256, D=256, H=512)
// Persistent-scan, R2: batched (pipelined) coherent staging loads.
//   grid = 256 WGs x 256 thr (1 WG/CU). WG (g,cs): g=bid&7 owns batch rows
//   [g*32,+32), cs=bid>>3 owns h-cols [cs*16,+16).
//   h/c exchanged via relaxed agent-scope atomics (MALL; bypass per-XCD L2).
//   R2 change: issue ALL h/c loads into registers first (two pure-load loops
//   -> single vmcnt drain), hide latency under x staging, then LDS writes.
//   R1 had a ds_write dependent on each atomic load -> serialized MALL
//   round trips (~10us/step of the 11.9us step time).
// ---------------------------------------------------------------------------

#define T_STEPS 256
#define BATCH   256
#define DIN     256
#define HID     512

typedef __attribute__((ext_vector_type(8))) __bf16 bf16x8;
typedef __attribute__((ext_vector_type(4))) float  f32x4;

#define MFMA(a,b,c) __builtin_amdgcn_mfma_f32_16x16x32_bf16((a),(b),(c),0,0,0)

// LDS layout (byte offsets). Row pads (+8 bf16) break power-of-2 bank strides.
#define H_S     0            // 32 x 1040B (520 bf16)
#define C_S     33280        // 32 x 1040B
#define X_S     66560        // 32 x 528B  (264 bf16)
#define WIN_S   83456        // 4 x 16 x 528B
#define Z_S     117248       // 18 tiles x 16x17 f32
#define LDS_SZ  136832
#define HSTR    1040
#define XSTR    528
#define ZROW    17

struct ScanP {
  const float *x, *tim;
  const float *Wi_w,*Wi_b,*Ui_w,*Ui_b,*bi;
  const float *Wf_w,*Wf_b,*Uf_w,*Uf_b,*bf_;
  const float *Wo_w,*Wo_b,*Uo_w,*Uo_b,*bo;
  const float *Wc_w,*Wc_b,*Uc_w,*Uc_b,*bc;
  const float *Wd_w,*b_dec;
  unsigned short *h_buf, *c_buf;   // bf16 bits, [2][256][512] double-buffered
  float *h_final;                  // [256][512] fp32
  unsigned int *flags;             // [8][32]
};

__device__ __forceinline__ float fsigm(float z){ return 1.f/(1.f + __expf(-z)); }
__device__ __forceinline__ float ftanh(float z){
  float e = __expf(-2.f*fabsf(z));
  float t = (1.f - e)/(1.f + e);
  return z < 0.f ? -t : t;
}
// Coherence-point (MALL) accesses: relaxed agent-scope atomics bypass the
// non-coherent per-XCD L2. No fences required anywhere.
__device__ __forceinline__ unsigned long long cload_u64(const unsigned long long* p){
  return __hip_atomic_load(p, __ATOMIC_RELAXED, __HIP_MEMORY_SCOPE_AGENT);
}
__device__ __forceinline__ unsigned int cload_u32(const unsigned int* p){
  return __hip_atomic_load(p, __ATOMIC_RELAXED, __HIP_MEMORY_SCOPE_AGENT);
}
__device__ __forceinline__ void cstore_u32(unsigned int* p, unsigned int v){
  __hip_atomic_store(p, v, __ATOMIC_RELAXED, __HIP_MEMORY_SCOPE_AGENT);
}

__device__ __forceinline__ bf16x8 wfrag8(const float* p){
  const float4* p4 = (const float4*)p;
  float4 a = p4[0], b = p4[1];
  bf16x8 r = { (__bf16)a.x,(__bf16)a.y,(__bf16)a.z,(__bf16)a.w,
               (__bf16)b.x,(__bf16)b.y,(__bf16)b.z,(__bf16)b.w };
  return r;
}
__device__ __forceinline__ void zstore(char* L, int tile, int lane, f32x4 v){
  float* p = (float*)(L + Z_S) + tile*(16*ZROW) + ((lane>>4)*4)*ZROW + (lane&15);
  p[0]=v[0]; p[ZROW]=v[1]; p[2*ZROW]=v[2]; p[3*ZROW]=v[3];
}
__device__ __forceinline__ float zread(const char* L, int tile, int r, int c){
  return ((const float*)(L + Z_S))[tile*(16*ZROW) + r*ZROW + c];
}

// Z tile ids: gate g U-part = g*2+m ; x-part = 8+4*m+g ; decomp = 16+m
__global__ void __launch_bounds__(256, 1) tlstm_scan(ScanP P)
{
  __shared__ __align__(16) char L[LDS_SZ];
  const int tid  = threadIdx.x;
  const int bid  = blockIdx.x;
  const int g    = bid & 7;          // row group (XCD-locality heuristic only)
  const int cs   = bid >> 3;         // 0..31
  const int rbase = g * 32;
  const int cbase = cs * 16;
  const int wave = tid >> 6, lane = tid & 63, lo = lane & 15, hi = lane >> 4;

  // ---- one-time: Win slices (4 gates x 16 cols x 256) fp32 -> bf16 -> LDS
  {
    const float* Wg = (tid < 64) ? P.Wi_w : (tid < 128) ? P.Wf_w
                    : (tid < 192) ? P.Wo_w : P.Wc_w;
    int wr = (tid >> 2) & 15, q = tid & 3;
    const float4* src = (const float4*)(Wg + (size_t)(cbase + wr) * DIN + q * 64);
    char* dst = L + WIN_S + (size_t)((tid >> 6) * 16 + wr) * XSTR + q * 128;
#pragma unroll
    for (int j = 0; j < 8; j++){
      float4 a = src[2*j], b = src[2*j+1];
      bf16x8 o = { (__bf16)a.x,(__bf16)a.y,(__bf16)a.z,(__bf16)a.w,
                   (__bf16)b.x,(__bf16)b.y,(__bf16)b.z,(__bf16)b.w };
      *(bf16x8*)(dst + j*16) = o;
    }
  }

  // ---- one-time: U/Wd B-fragments -> registers (loop-invariant, ~128 VGPR)
  bf16x8 bP[16], bQ[16];
  {
    const float* Pw = (wave == 0) ? P.Ui_w : (wave == 1) ? P.Uo_w : P.Wd_w;
#pragma unroll
    for (int kc = 0; kc < 16; kc++)
      bP[kc] = wfrag8(Pw + (size_t)(cbase + lo) * HID + kc * 32 + hi * 8);
    if (wave < 2){
      const float* Qw = (wave == 0) ? P.Uf_w : P.Uc_w;
#pragma unroll
      for (int kc = 0; kc < 16; kc++)
        bQ[kc] = wfrag8(Qw + (size_t)(cbase + lo) * HID + kc * 32 + hi * 8);
    }
  }

  // ---- per-thread elementwise ownership: row=tid>>3, cols cbase+(tid&7)*2..+1
  const int erow = tid >> 3;
  const int ecp  = (tid & 7) * 2;
  float bias_i[2], bias_f[2], bias_o[2], bias_c[2], bias_d[2], cr[2];
#pragma unroll
  for (int e = 0; e < 2; e++){
    int c = cbase + ecp + e;
    bias_i[e] = P.Wi_b[c] + P.bi[c]  + P.Ui_b[c];
    bias_f[e] = P.Wf_b[c] + P.bf_[c] + P.Uf_b[c];
    bias_o[e] = P.Wo_b[c] + P.bo[c]  + P.Uo_b[c];
    bias_c[e] = P.Wc_b[c] + P.bc[c]  + P.Uc_b[c];
    bias_d[e] = P.b_dec[c];
    cr[e] = 0.f;
  }

  unsigned int* gflags = P.flags + g * 32;
  const int member = cs;
  const int srow = tid >> 3, sseg = tid & 7;   // staging map

#pragma unroll 1
  for (int t = 0; t < T_STEPS; ++t){
    const int rp = t & 1;
    const unsigned short* hprev = P.h_buf + (size_t)rp * BATCH * HID;
    const unsigned short* cprev = P.c_buf + (size_t)rp * BATCH * HID;
    unsigned short* hnext = P.h_buf + (size_t)(rp ^ 1) * BATCH * HID;
    unsigned short* cnext = P.c_buf + (size_t)(rp ^ 1) * BATCH * HID;

    // x slice does not depend on peers: issue its global loads before polling
    const float4* xsrc = (const float4*)(P.x + ((size_t)(rbase + srow) * T_STEPS + t) * DIN + sseg * 32);
    float4 xv[8];
#pragma unroll
    for (int j = 0; j < 8; j++) xv[j] = xsrc[j];

    // ---- group barrier: wave 0 polls until all 32 peers finished step t-1
    if (wave == 0){
      bool done = false;
      while (!done){
        unsigned int v = 0xFFFFFFFFu;
        if (lane < 32) v = cload_u32(gflags + lane);
        done = (bool)__all((int)(lane >= 32 || v >= (unsigned int)t));
        if (!done) __builtin_amdgcn_s_sleep(4);
      }
    }
    __syncthreads();      // releases waves 1-3; also: old LDS uses finished

    // ---- issue ALL h/c coherent loads into registers (pure-load loops ->
    //      batched issue, one vmcnt drain at first use, no per-load stalls)
    unsigned long long hv[16], cvv[16];
    {
      const unsigned long long* hs = (const unsigned long long*)(hprev + (size_t)(rbase + srow) * HID + sseg * 64);
      const unsigned long long* cspp = (const unsigned long long*)(cprev + (size_t)(rbase + srow) * HID + sseg * 64);
#pragma unroll
      for (int j = 0; j < 16; j++) hv[j] = cload_u64(hs + j);
#pragma unroll
      for (int j = 0; j < 16; j++) cvv[j] = cload_u64(cspp + j);
    }

    // ---- stage x (fp32 -> bf16) — fills the h/c load shadow
    {
      char* dst = L + X_S + srow * XSTR + sseg * 64;
#pragma unroll
      for (int j = 0; j < 4; j++){
        float4 a = xv[2*j], b = xv[2*j+1];
        bf16x8 o = { (__bf16)a.x,(__bf16)a.y,(__bf16)a.z,(__bf16)a.w,
                     (__bf16)b.x,(__bf16)b.y,(__bf16)b.z,(__bf16)b.w };
        *(bf16x8*)(dst + j*16) = o;
      }
    }
    // ---- now commit h/c to LDS (single drain covers all 32 loads)
    {
      unsigned long long* hd = (unsigned long long*)(L + H_S + srow * HSTR + sseg * 128);
      unsigned long long* cd = (unsigned long long*)(L + C_S + srow * HSTR + sseg * 128);
#pragma unroll
      for (int j = 0; j < 16; j++) hd[j] = hv[j];
#pragma unroll
      for (int j = 0; j < 16; j++) cd[j] = cvv[j];
    }
    __syncthreads();

    // ---- MFMA phase
    if (wave < 2){
      // wave0: Zi,Zf (U-parts, both M-tiles); wave1: Zo,Zc
      f32x4 z0 = {0.f,0.f,0.f,0.f}, z1 = z0, z2 = z0, z3 = z0;
#pragma unroll
      for (int kc = 0; kc < 16; kc++){
        bf16x8 a0 = *(const bf16x8*)(L + H_S + lo * HSTR        + kc*64 + hi*16);
        bf16x8 a1 = *(const bf16x8*)(L + H_S + (16 + lo) * HSTR + kc*64 + hi*16);
        z0 = MFMA(a0, bP[kc], z0);
        z1 = MFMA(a1, bP[kc], z1);
        z2 = MFMA(a0, bQ[kc], z2);
        z3 = MFMA(a1, bQ[kc], z3);
      }
      int tb = wave * 4;   // tiles {0..3} = Zi m0,m1, Zf m0,m1 ; {4..7} = Zo,Zc
      zstore(L, tb+0, lane, z0); zstore(L, tb+1, lane, z1);
      zstore(L, tb+2, lane, z2); zstore(L, tb+3, lane, z3);
    } else {
      // wave2: x-projections m0 (4 gates) + decomp m0 ; wave3: same for m1
      const int m = wave - 2;
      f32x4 xi = {0.f,0.f,0.f,0.f}, xf = xi, xo = xi, xcg = xi, zd = xi;
#pragma unroll
      for (int q = 0; q < 8; q++){
        bf16x8 a  = *(const bf16x8*)(L + X_S   + (m*16 + lo) * XSTR + q*64 + hi*16);
        bf16x8 w0 = *(const bf16x8*)(L + WIN_S + (0*16 + lo) * XSTR + q*64 + hi*16);
        bf16x8 w1 = *(const bf16x8*)(L + WIN_S + (1*16 + lo) * XSTR + q*64 + hi*16);
        bf16x8 w2 = *(const bf16x8*)(L + WIN_S + (2*16 + lo) * XSTR + q*64 + hi*16);
        bf16x8 w3 = *(const bf16x8*)(L + WIN_S + (3*16 + lo) * XSTR + q*64 + hi*16);
        xi  = MFMA(a, w0, xi);  xf  = MFMA(a, w1, xf);
        xo  = MFMA(a, w2, xo);  xcg = MFMA(a, w3, xcg);
      }
#pragma unroll
      for (int kc = 0; kc < 16; kc++){
        bf16x8 a = *(const bf16x8*)(L + C_S + (m*16 + lo) * HSTR + kc*64 + hi*16);
        zd = MFMA(a, bP[kc], zd);
      }
      zstore(L, 8+4*m+0, lane, xi);  zstore(L, 8+4*m+1, lane, xf);
      zstore(L, 8+4*m+2, lane, xo);  zstore(L, 8+4*m+3, lane, xcg);
      zstore(L, 16+m,    lane, zd);
    }
    __syncthreads();

    // ---- elementwise gate math (fp32), publish h/c bf16 via MALL
    {
      const int m = erow >> 4, r16 = erow & 15;
      float tv   = P.tim[(size_t)(rbase + erow) * T_STEPS + t];
      float Tmap = 1.f / __logf(tv + 2.7183f);
      unsigned int hpk = 0, cpk = 0;
      float hv2[2];
#pragma unroll
      for (int e = 0; e < 2; e++){
        int col = ecp + e;
        float zi = zread(L, 0*2+m, r16, col) + zread(L, 8+4*m+0, r16, col) + bias_i[e];
        float zf = zread(L, 1*2+m, r16, col) + zread(L, 8+4*m+1, r16, col) + bias_f[e];
        float zo = zread(L, 2*2+m, r16, col) + zread(L, 8+4*m+2, r16, col) + bias_o[e];
        float zc = zread(L, 3*2+m, r16, col) + zread(L, 8+4*m+3, r16, col) + bias_c[e];
        float zdv = zread(L, 16+m, r16, col) + bias_d[e];
        float cst = ftanh(zdv);
        float c1  = cr[e] - cst + Tmap * cst;
        float ig = fsigm(zi), fg = fsigm(zf), og = fsigm(zo);
        float ch = ftanh(zc);
        float c2 = fg * c1 + ig * ch;
        float hv_ = og * ftanh(c2);
        cr[e] = c2; hv2[e] = hv_;
        hpk |= (unsigned int)__builtin_bit_cast(unsigned short, (__bf16)hv_) << (16*e);
        cpk |= (unsigned int)__builtin_bit_cast(unsigned short, (__bf16)c2) << (16*e);
      }
      size_t off = (size_t)(rbase + erow) * HID + cbase + ecp;
      cstore_u32((unsigned int*)(hnext + off), hpk);
      cstore_u32((unsigned int*)(cnext + off), cpk);
      if (t == T_STEPS - 1){
        P.h_final[off]     = hv2[0];
        P.h_final[off + 1] = hv2[1];
      }
    }
    // release: each wave drains its own (MALL-acked) stores, then barrier,
    // then the flag store — data is globally visible before the flag issues.
    asm volatile("s_waitcnt vmcnt(0)" ::: "memory");
    __syncthreads();
    if (tid == 0) cstore_u32(gflags + member, (unsigned int)(t + 1));
  }
}

// ---------------- head: out = relu(hT @ fc_w^T + fc_b) @ cls_w^T + cls_b ----
__global__ void __launch_bounds__(256) tlstm_head(const float* __restrict__ hfin,
    const float* __restrict__ fc_w, const float* __restrict__ fc_b,
    const float* __restrict__ cls_w, const float* __restrict__ cls_b,
    float* __restrict__ out)
{
  __shared__ float hrow[512];
  __shared__ float fcv[256];
  const int b = blockIdx.x, tid = threadIdx.x;
  ((float2*)hrow)[tid] = ((const float2*)(hfin + (size_t)b * 512))[tid];
  __syncthreads();
  {
    const float4* w4 = (const float4*)(fc_w + (size_t)tid * 512);
    const float4* h4 = (const float4*)hrow;
    float acc = fc_b[tid];
#pragma unroll 4
    for (int k = 0; k < 128; k++){
      float4 w = w4[k], h = h4[k];
      acc += w.x*h.x + w.y*h.y + w.z*h.z + w.w*h.w;
    }
    fcv[tid] = fmaxf(acc, 0.f);
  }
  __syncthreads();
  const int wave = tid >> 6, lane = tid & 63;
  if (wave < 2){
    const float* cw = cls_w + wave * 256;
    float s = 0.f;
#pragma unroll
    for (int j = lane; j < 256; j += 64) s += fcv[j] * cw[j];
#pragma unroll
    for (int off = 32; off > 0; off >>= 1) s += __shfl_down(s, off, 64);
    if (lane == 0) out[b * 2 + wave] = s + cls_b[wave];
  }
}

// ---------------------------------------------------------------------------
extern "C" void kernel_launch(void* const* d_in, const int* in_sizes, int n_in,
                              void* d_out, int out_size, void* d_ws, size_t ws_size,
                              hipStream_t stream)
{
  (void)in_sizes; (void)n_in; (void)out_size; (void)ws_size;

  ScanP P;
  P.x    = (const float*)d_in[0];
  P.tim  = (const float*)d_in[1];
  P.Wi_w = (const float*)d_in[2];  P.Wi_b = (const float*)d_in[3];
  P.Ui_w = (const float*)d_in[4];  P.Ui_b = (const float*)d_in[5];  P.bi  = (const float*)d_in[6];
  P.Wf_w = (const float*)d_in[7];  P.Wf_b = (const float*)d_in[8];
  P.Uf_w = (const float*)d_in[9];  P.Uf_b = (const float*)d_in[10]; P.bf_ = (const float*)d_in[11];
  P.Wo_w = (const float*)d_in[12]; P.Wo_b = (const float*)d_in[13];
  P.Uo_w = (const float*)d_in[14]; P.Uo_b = (const float*)d_in[15]; P.bo  = (const float*)d_in[16];
  P.Wc_w = (const float*)d_in[17]; P.Wc_b = (const float*)d_in[18];
  P.Uc_w = (const float*)d_in[19]; P.Uc_b = (const float*)d_in[20]; P.bc  = (const float*)d_in[21];
  P.Wd_w = (const float*)d_in[22]; P.b_dec = (const float*)d_in[23];
  const float* fc_w  = (const float*)d_in[24];
  const float* fc_b  = (const float*)d_in[25];
  const float* cls_w = (const float*)d_in[26];
  const float* cls_b = (const float*)d_in[27];

  // workspace layout: [h_buf 512K][c_buf 512K][flags 1K][h_final 512K]
  unsigned short* h_buf = (unsigned short*)d_ws;                 // 2*256*512 bf16
  unsigned short* c_buf = h_buf + 2 * BATCH * HID;               // 2*256*512 bf16
  unsigned int* flags   = (unsigned int*)(c_buf + 2 * BATCH * HID); // 256 flags
  float* h_final        = (float*)((char*)flags + 1024);         // 256*512 f32
  P.h_buf = h_buf; P.c_buf = c_buf; P.h_final = h_final; P.flags = flags;

  const size_t zero_bytes = (size_t)2 * BATCH * HID * 2 * 2 + 1024; // h,c,flags
  hipMemsetAsync(d_ws, 0, zero_bytes, stream);

  hipLaunchKernelGGL(tlstm_scan, dim3(256), dim3(256), 0, stream, P);
  hipLaunchKernelGGL(tlstm_head, dim3(256), dim3(256), 0, stream,
                     h_final, fc_w, fc_b, cls_w, cls_b, (float*)d_out);
}

// Round 4
// 1189.300 us; speedup vs baseline: 7.3369x; 2.3813x over previous
//
#include <hip/hip_runtime.h>

// ---------------------------------------------------------------------------
// TLSTM  (B=256, T=256, D=256, H=512)
// Persistent-scan, R3: normal-path cache-bypass exchange (no atomics).
//   grid = 256 WGs x 256 thr (1 WG/CU). WG (g,cs): g=bid&7 owns batch rows
//   [g*32,+32), cs=bid>>3 owns h-cols [cs*16,+16).
//   h/c exchanged through the MALL via inline-asm global_load_dwordx4 /
//   global_store_dwordx2 with sc0 sc1 (bypass non-coherent L1/L2, normal
//   memory pipeline -- NOT the rate-limited atomic path R1/R2 used).
//   Packing: one u64 per (row, col-pair) = [h0|h1 : c0|c1].
//   Release: vmcnt(0) drain -> barrier -> flag store (sc0 sc1).
//   Staging LDS map: lane = 16B granule within row -> 2 lanes/bank (free),
//   replacing the old 8-way-conflict ds_write_b64 pattern.
// ---------------------------------------------------------------------------

#define T_STEPS 256
#define BATCH   256
#define DIN     256
#define HID     512

typedef __attribute__((ext_vector_type(8))) __bf16 bf16x8;
typedef __attribute__((ext_vector_type(4))) float  f32x4;

#define MFMA(a,b,c) __builtin_amdgcn_mfma_f32_16x16x32_bf16((a),(b),(c),0,0,0)

// LDS layout (byte offsets).
#define H_S     0            // 32 x 1040B (520 bf16)
#define C_S     33280        // 32 x 1040B
#define X_S     66560        // 32 x 528B  (264 bf16)
#define WIN_S   83456        // 4 x 16 x 528B
#define Z_S     117248       // 18 tiles x 16x17 f32
#define LDS_SZ  136832
#define HSTR    1040
#define XSTR    528
#define ZROW    17

struct ScanP {
  const float *x, *tim;
  const float *Wi_w,*Wi_b,*Ui_w,*Ui_b,*bi;
  const float *Wf_w,*Wf_b,*Uf_w,*Uf_b,*bf_;
  const float *Wo_w,*Wo_b,*Uo_w,*Uo_b,*bo;
  const float *Wc_w,*Wc_b,*Uc_w,*Uc_b,*bc;
  const float *Wd_w,*b_dec;
  unsigned long long *hc_buf;      // [2][256 rows][256 col-pairs] u64
  float *h_final;                  // [256][512] fp32
  unsigned int *flags;             // [8][32]
};

__device__ __forceinline__ float fsigm(float z){ return 1.f/(1.f + __expf(-z)); }
__device__ __forceinline__ float ftanh(float z){
  float e = __expf(-2.f*fabsf(z));
  float t = (1.f - e)/(1.f + e);
  return z < 0.f ? -t : t;
}

// --- device-coherent (MALL) accesses on the NORMAL memory path -------------
__device__ __forceinline__ uint4 cload16(const void* p){
  uint4 r;
  asm volatile("global_load_dwordx4 %0, %1, off sc0 sc1"
               : "=v"(r) : "v"(p) : "memory");
  return r;
}
__device__ __forceinline__ void cstore8(void* p, unsigned long long v){
  asm volatile("global_store_dwordx2 %0, %1, off sc0 sc1"
               :: "v"(p), "v"(v) : "memory");
}
__device__ __forceinline__ void cstore4(void* p, unsigned int v){
  asm volatile("global_store_dword %0, %1, off sc0 sc1"
               :: "v"(p), "v"(v) : "memory");
}
__device__ __forceinline__ unsigned int pollload(const unsigned int* p){
  unsigned int r;
  asm volatile("global_load_dword %0, %1, off sc0 sc1\n\t"
               "s_waitcnt vmcnt(0)"
               : "=v"(r) : "v"(p) : "memory");
  return r;
}

__device__ __forceinline__ bf16x8 wfrag8(const float* p){
  const float4* p4 = (const float4*)p;
  float4 a = p4[0], b = p4[1];
  bf16x8 r = { (__bf16)a.x,(__bf16)a.y,(__bf16)a.z,(__bf16)a.w,
               (__bf16)b.x,(__bf16)b.y,(__bf16)b.z,(__bf16)b.w };
  return r;
}
__device__ __forceinline__ void zstore(char* L, int tile, int lane, f32x4 v){
  float* p = (float*)(L + Z_S) + tile*(16*ZROW) + ((lane>>4)*4)*ZROW + (lane&15);
  p[0]=v[0]; p[ZROW]=v[1]; p[2*ZROW]=v[2]; p[3*ZROW]=v[3];
}
__device__ __forceinline__ float zread(const char* L, int tile, int r, int c){
  return ((const float*)(L + Z_S))[tile*(16*ZROW) + r*ZROW + c];
}

// Z tile ids: gate g U-part = g*2+m ; x-part = 8+4*m+g ; decomp = 16+m
__global__ void __launch_bounds__(256, 1) tlstm_scan(ScanP P)
{
  __shared__ __align__(16) char L[LDS_SZ];
  const int tid  = threadIdx.x;
  const int bid  = blockIdx.x;
  const int g    = bid & 7;          // row group (XCD-locality heuristic only)
  const int cs   = bid >> 3;         // 0..31
  const int rbase = g * 32;
  const int cbase = cs * 16;
  const int wave = tid >> 6, lane = tid & 63, lo = lane & 15, hi = lane >> 4;

  // ---- one-time: Win slices (4 gates x 16 cols x 256) fp32 -> bf16 -> LDS
  {
    const float* Wg = (tid < 64) ? P.Wi_w : (tid < 128) ? P.Wf_w
                    : (tid < 192) ? P.Wo_w : P.Wc_w;
    int wr = (tid >> 2) & 15, q = tid & 3;
    const float4* src = (const float4*)(Wg + (size_t)(cbase + wr) * DIN + q * 64);
    char* dst = L + WIN_S + (size_t)((tid >> 6) * 16 + wr) * XSTR + q * 128;
#pragma unroll
    for (int j = 0; j < 8; j++){
      float4 a = src[2*j], b = src[2*j+1];
      bf16x8 o = { (__bf16)a.x,(__bf16)a.y,(__bf16)a.z,(__bf16)a.w,
                   (__bf16)b.x,(__bf16)b.y,(__bf16)b.z,(__bf16)b.w };
      *(bf16x8*)(dst + j*16) = o;
    }
  }

  // ---- one-time: U/Wd B-fragments -> registers (loop-invariant, ~128 VGPR)
  bf16x8 bP[16], bQ[16];
  {
    const float* Pw = (wave == 0) ? P.Ui_w : (wave == 1) ? P.Uo_w : P.Wd_w;
#pragma unroll
    for (int kc = 0; kc < 16; kc++)
      bP[kc] = wfrag8(Pw + (size_t)(cbase + lo) * HID + kc * 32 + hi * 8);
    if (wave < 2){
      const float* Qw = (wave == 0) ? P.Uf_w : P.Uc_w;
#pragma unroll
      for (int kc = 0; kc < 16; kc++)
        bQ[kc] = wfrag8(Qw + (size_t)(cbase + lo) * HID + kc * 32 + hi * 8);
    }
  }

  // ---- per-thread elementwise ownership: row=tid>>3, cols cbase+(tid&7)*2..+1
  const int erow = tid >> 3;
  const int ecp  = (tid & 7) * 2;
  float bias_i[2], bias_f[2], bias_o[2], bias_c[2], bias_d[2], cr[2];
#pragma unroll
  for (int e = 0; e < 2; e++){
    int c = cbase + ecp + e;
    bias_i[e] = P.Wi_b[c] + P.bi[c]  + P.Ui_b[c];
    bias_f[e] = P.Wf_b[c] + P.bf_[c] + P.Uf_b[c];
    bias_o[e] = P.Wo_b[c] + P.bo[c]  + P.Uo_b[c];
    bias_c[e] = P.Wc_b[c] + P.bc[c]  + P.Uc_b[c];
    bias_d[e] = P.b_dec[c];
    cr[e] = 0.f;
  }

  unsigned int* gflags = P.flags + g * 32;
  const int member = cs;
  const int srow = tid >> 3, sseg = tid & 7;   // x staging map

#pragma unroll 1
  for (int t = 0; t < T_STEPS; ++t){
    const int rp = t & 1;
    const unsigned long long* hcprev = P.hc_buf + (size_t)rp * BATCH * 256;
    unsigned long long* hcnext = P.hc_buf + (size_t)(rp ^ 1) * BATCH * 256;

    // x slice + tim do not depend on peers: issue before polling
    const float4* xsrc = (const float4*)(P.x + ((size_t)(rbase + srow) * T_STEPS + t) * DIN + sseg * 32);
    float4 xv[8];
#pragma unroll
    for (int j = 0; j < 8; j++) xv[j] = xsrc[j];
    float tv = P.tim[(size_t)(rbase + erow) * T_STEPS + t];

    // ---- group barrier: wave 0 polls until all 32 peers finished step t-1
    if (wave == 0){
      bool done = false;
      while (!done){
        unsigned int v = 0xFFFFFFFFu;
        if (lane < 32) v = pollload(gflags + lane);
        done = (bool)__all((int)(lane >= 32 || v >= (unsigned int)t));
        if (!done) __builtin_amdgcn_s_sleep(1);
      }
    }
    __syncthreads();      // releases waves 1-3; also: old LDS uses finished

    // ---- issue all h/c coherent loads (16 x dwordx4 per thread, in flight)
    uint4 gr[16];
    {
      const char* src = (const char*)hcprev + (size_t)(rbase + wave * 8) * 2048;
#pragma unroll
      for (int j = 0; j < 16; j++){
        int row = j >> 1;                       // within this wave's 8 rows
        int gg  = (j & 1) * 64 + lane;          // 16B granule within row
        gr[j] = cload16(src + (size_t)row * 2048 + (size_t)gg * 16);
      }
    }

    // ---- stage x (fp32 -> bf16) — fills the h/c load shadow
    {
      char* dst = L + X_S + srow * XSTR + sseg * 64;
#pragma unroll
      for (int j = 0; j < 4; j++){
        float4 a = xv[2*j], b = xv[2*j+1];
        bf16x8 o = { (__bf16)a.x,(__bf16)a.y,(__bf16)a.z,(__bf16)a.w,
                     (__bf16)b.x,(__bf16)b.y,(__bf16)b.z,(__bf16)b.w };
        *(bf16x8*)(dst + j*16) = o;
      }
    }

    asm volatile("s_waitcnt vmcnt(0)" ::: "memory");
    __builtin_amdgcn_sched_barrier(0);

    // ---- commit h/c to LDS. granule gg covers cols 4gg..4gg+3:
    //      gr = [h01, c01, h23, c23] -> h u64 {x,z}, c u64 {y,w}
    {
#pragma unroll
      for (int j = 0; j < 16; j++){
        int row = wave * 8 + (j >> 1);
        int gg  = (j & 1) * 64 + lane;
        *(uint2*)(L + H_S + row * HSTR + gg * 8) = uint2{gr[j].x, gr[j].z};
        *(uint2*)(L + C_S + row * HSTR + gg * 8) = uint2{gr[j].y, gr[j].w};
      }
    }
    __syncthreads();

    // ---- MFMA phase
    if (wave < 2){
      // wave0: Zi,Zf (U-parts, both M-tiles); wave1: Zo,Zc
      f32x4 z0 = {0.f,0.f,0.f,0.f}, z1 = z0, z2 = z0, z3 = z0;
#pragma unroll
      for (int kc = 0; kc < 16; kc++){
        bf16x8 a0 = *(const bf16x8*)(L + H_S + lo * HSTR        + kc*64 + hi*16);
        bf16x8 a1 = *(const bf16x8*)(L + H_S + (16 + lo) * HSTR + kc*64 + hi*16);
        z0 = MFMA(a0, bP[kc], z0);
        z1 = MFMA(a1, bP[kc], z1);
        z2 = MFMA(a0, bQ[kc], z2);
        z3 = MFMA(a1, bQ[kc], z3);
      }
      int tb = wave * 4;   // tiles {0..3} = Zi m0,m1, Zf m0,m1 ; {4..7} = Zo,Zc
      zstore(L, tb+0, lane, z0); zstore(L, tb+1, lane, z1);
      zstore(L, tb+2, lane, z2); zstore(L, tb+3, lane, z3);
    } else {
      // wave2: x-projections m0 (4 gates) + decomp m0 ; wave3: same for m1
      const int m = wave - 2;
      f32x4 xi = {0.f,0.f,0.f,0.f}, xf = xi, xo = xi, xcg = xi, zd = xi;
#pragma unroll
      for (int q = 0; q < 8; q++){
        bf16x8 a  = *(const bf16x8*)(L + X_S   + (m*16 + lo) * XSTR + q*64 + hi*16);
        bf16x8 w0 = *(const bf16x8*)(L + WIN_S + (0*16 + lo) * XSTR + q*64 + hi*16);
        bf16x8 w1 = *(const bf16x8*)(L + WIN_S + (1*16 + lo) * XSTR + q*64 + hi*16);
        bf16x8 w2 = *(const bf16x8*)(L + WIN_S + (2*16 + lo) * XSTR + q*64 + hi*16);
        bf16x8 w3 = *(const bf16x8*)(L + WIN_S + (3*16 + lo) * XSTR + q*64 + hi*16);
        xi  = MFMA(a, w0, xi);  xf  = MFMA(a, w1, xf);
        xo  = MFMA(a, w2, xo);  xcg = MFMA(a, w3, xcg);
      }
#pragma unroll
      for (int kc = 0; kc < 16; kc++){
        bf16x8 a = *(const bf16x8*)(L + C_S + (m*16 + lo) * HSTR + kc*64 + hi*16);
        zd = MFMA(a, bP[kc], zd);
      }
      zstore(L, 8+4*m+0, lane, xi);  zstore(L, 8+4*m+1, lane, xf);
      zstore(L, 8+4*m+2, lane, xo);  zstore(L, 8+4*m+3, lane, xcg);
      zstore(L, 16+m,    lane, zd);
    }
    __syncthreads();

    // ---- elementwise gate math (fp32), publish h/c packed u64 (sc0 sc1)
    {
      const int m = erow >> 4, r16 = erow & 15;
      float Tmap = 1.f / __logf(tv + 2.7183f);
      unsigned int hpk = 0, cpk = 0;
      float hv2[2];
#pragma unroll
      for (int e = 0; e < 2; e++){
        int col = ecp + e;
        float zi = zread(L, 0*2+m, r16, col) + zread(L, 8+4*m+0, r16, col) + bias_i[e];
        float zf = zread(L, 1*2+m, r16, col) + zread(L, 8+4*m+1, r16, col) + bias_f[e];
        float zo = zread(L, 2*2+m, r16, col) + zread(L, 8+4*m+2, r16, col) + bias_o[e];
        float zc = zread(L, 3*2+m, r16, col) + zread(L, 8+4*m+3, r16, col) + bias_c[e];
        float zdv = zread(L, 16+m, r16, col) + bias_d[e];
        float cst = ftanh(zdv);
        float c1  = cr[e] - cst + Tmap * cst;
        float ig = fsigm(zi), fg = fsigm(zf), og = fsigm(zo);
        float ch = ftanh(zc);
        float c2 = fg * c1 + ig * ch;
        float hv_ = og * ftanh(c2);
        cr[e] = c2; hv2[e] = hv_;
        hpk |= (unsigned int)__builtin_bit_cast(unsigned short, (__bf16)hv_) << (16*e);
        cpk |= (unsigned int)__builtin_bit_cast(unsigned short, (__bf16)c2) << (16*e);
      }
      if (t < T_STEPS - 1){
        size_t off = ((size_t)(rbase + erow) * 256 + (cbase >> 1) + (tid & 7)) * 8;
        cstore8((char*)hcnext + off,
                (unsigned long long)hpk | ((unsigned long long)cpk << 32));
      } else {
        size_t off = (size_t)(rbase + erow) * HID + cbase + ecp;
        P.h_final[off]     = hv2[0];
        P.h_final[off + 1] = hv2[1];
      }
    }
    // release: drain own MALL-acked stores, barrier, then flag store
    if (t < T_STEPS - 1){
      asm volatile("s_waitcnt vmcnt(0)" ::: "memory");
      __builtin_amdgcn_sched_barrier(0);
      __syncthreads();
      if (tid == 0) cstore4(gflags + member, (unsigned int)(t + 1));
    }
  }
}

// ---------------- head: out = relu(hT @ fc_w^T + fc_b) @ cls_w^T + cls_b ----
__global__ void __launch_bounds__(256) tlstm_head(const float* __restrict__ hfin,
    const float* __restrict__ fc_w, const float* __restrict__ fc_b,
    const float* __restrict__ cls_w, const float* __restrict__ cls_b,
    float* __restrict__ out)
{
  __shared__ float hrow[512];
  __shared__ float fcv[256];
  const int b = blockIdx.x, tid = threadIdx.x;
  ((float2*)hrow)[tid] = ((const float2*)(hfin + (size_t)b * 512))[tid];
  __syncthreads();
  {
    const float4* w4 = (const float4*)(fc_w + (size_t)tid * 512);
    const float4* h4 = (const float4*)hrow;
    float acc = fc_b[tid];
#pragma unroll 4
    for (int k = 0; k < 128; k++){
      float4 w = w4[k], h = h4[k];
      acc += w.x*h.x + w.y*h.y + w.z*h.z + w.w*h.w;
    }
    fcv[tid] = fmaxf(acc, 0.f);
  }
  __syncthreads();
  const int wave = tid >> 6, lane = tid & 63;
  if (wave < 2){
    const float* cw = cls_w + wave * 256;
    float s = 0.f;
#pragma unroll
    for (int j = lane; j < 256; j += 64) s += fcv[j] * cw[j];
#pragma unroll
    for (int off = 32; off > 0; off >>= 1) s += __shfl_down(s, off, 64);
    if (lane == 0) out[b * 2 + wave] = s + cls_b[wave];
  }
}

// ---------------------------------------------------------------------------
extern "C" void kernel_launch(void* const* d_in, const int* in_sizes, int n_in,
                              void* d_out, int out_size, void* d_ws, size_t ws_size,
                              hipStream_t stream)
{
  (void)in_sizes; (void)n_in; (void)out_size; (void)ws_size;

  ScanP P;
  P.x    = (const float*)d_in[0];
  P.tim  = (const float*)d_in[1];
  P.Wi_w = (const float*)d_in[2];  P.Wi_b = (const float*)d_in[3];
  P.Ui_w = (const float*)d_in[4];  P.Ui_b = (const float*)d_in[5];  P.bi  = (const float*)d_in[6];
  P.Wf_w = (const float*)d_in[7];  P.Wf_b = (const float*)d_in[8];
  P.Uf_w = (const float*)d_in[9];  P.Uf_b = (const float*)d_in[10]; P.bf_ = (const float*)d_in[11];
  P.Wo_w = (const float*)d_in[12]; P.Wo_b = (const float*)d_in[13];
  P.Uo_w = (const float*)d_in[14]; P.Uo_b = (const float*)d_in[15]; P.bo  = (const float*)d_in[16];
  P.Wc_w = (const float*)d_in[17]; P.Wc_b = (const float*)d_in[18];
  P.Uc_w = (const float*)d_in[19]; P.Uc_b = (const float*)d_in[20]; P.bc  = (const float*)d_in[21];
  P.Wd_w = (const float*)d_in[22]; P.b_dec = (const float*)d_in[23];
  const float* fc_w  = (const float*)d_in[24];
  const float* fc_b  = (const float*)d_in[25];
  const float* cls_w = (const float*)d_in[26];
  const float* cls_b = (const float*)d_in[27];

  // workspace layout: [hc_buf 2x512K][flags 1K][h_final 512K]
  unsigned long long* hc_buf = (unsigned long long*)d_ws;        // 2*256*256 u64
  unsigned int* flags = (unsigned int*)(hc_buf + 2 * BATCH * 256);
  float* h_final = (float*)((char*)flags + 1024);                // 256*512 f32
  P.hc_buf = hc_buf; P.h_final = h_final; P.flags = flags;

  const size_t zero_bytes = (size_t)2 * BATCH * 256 * 8 + 1024;  // hc + flags
  hipMemsetAsync(d_ws, 0, zero_bytes, stream);

  hipLaunchKernelGGL(tlstm_scan, dim3(256), dim3(256), 0, stream, P);
  hipLaunchKernelGGL(tlstm_head, dim3(256), dim3(256), 0, stream,
                     h_final, fc_w, fc_b, cls_w, cls_b, (float*)d_out);
}

// Round 7
// 1158.107 us; speedup vs baseline: 7.5345x; 1.0269x over previous
//
#include <hip/hip_runtime.h>

// ---------------------------------------------------------------------------
// TLSTM  (B=256, T=256, D=256, H=512)
// Persistent-scan, R6 = R3 base (proven PASS, 1189us) + ONE delta:
//   flag handshake (3 serialized fabric RTs/step) replaced by self-validating
//   tagged publishes. Each exchanged u64 = [h0,h1|c0,c1] bf16 carries the
//   2-bit step tag w(t)=(t+1)&3 in the LSBs of ALL FOUR bf16 elements
//   (bit0+bit16 of each dword) -> every 32-bit word independently validates,
//   robust even if a dwordx2 tears into two dword transactions.
//   Consumer = R3's exact batched sc0sc1 load + vmcnt(0), plus validate+retry
//   (guarded: 64K iterations -> proceeds, converts protocol bugs into fast
//   visible failure, never a hang). Producers never wait on consumers ->
//   livelock/deadlock-free. Memset-zero tags == w(-1)=0 match t=0.
//   Everything else (LDS map, staging, MFMA, elementwise, ws layout) is R3.
// ---------------------------------------------------------------------------

#define T_STEPS 256
#define BATCH   256
#define DIN     256
#define HID     512

typedef __attribute__((ext_vector_type(8))) __bf16 bf16x8;
typedef __attribute__((ext_vector_type(4))) float  f32x4;

#define MFMA(a,b,c) __builtin_amdgcn_mfma_f32_16x16x32_bf16((a),(b),(c),0,0,0)

// LDS layout (byte offsets).
#define H_S     0            // 32 x 1040B (520 bf16)
#define C_S     33280        // 32 x 1040B
#define X_S     66560        // 32 x 528B  (264 bf16)
#define WIN_S   83456        // 4 x 16 x 528B
#define Z_S     117248       // 18 tiles x 16x17 f32
#define LDS_SZ  136832
#define HSTR    1040
#define XSTR    528
#define ZROW    17

struct ScanP {
  const float *x, *tim;
  const float *Wi_w,*Wi_b,*Ui_w,*Ui_b,*bi;
  const float *Wf_w,*Wf_b,*Uf_w,*Uf_b,*bf_;
  const float *Wo_w,*Wo_b,*Uo_w,*Uo_b,*bo;
  const float *Wc_w,*Wc_b,*Uc_w,*Uc_b,*bc;
  const float *Wd_w,*b_dec;
  unsigned long long *hc_buf;      // [2][256 rows][256 col-pairs] u64
  float *h_final;                  // [256][512] fp32
  unsigned int *flags;             // [8][32] (kept from R3 layout; unused)
};

__device__ __forceinline__ float fsigm(float z){ return 1.f/(1.f + __expf(-z)); }
__device__ __forceinline__ float ftanh(float z){
  float e = __expf(-2.f*fabsf(z));
  float t = (1.f - e)/(1.f + e);
  return z < 0.f ? -t : t;
}

// device-coherent via MALL (bypass non-coherent L1+L2) — R3-proven path
__device__ __forceinline__ uint4 cld16(const void* p){
  uint4 r;
  asm volatile("global_load_dwordx4 %0, %1, off sc0 sc1"
               : "=v"(r) : "v"(p) : "memory");
  return r;
}
__device__ __forceinline__ void cst8(void* p, unsigned long long v){
  asm volatile("global_store_dwordx2 %0, %1, off sc0 sc1"
               :: "v"(p), "v"(v) : "memory");
}

__device__ __forceinline__ bf16x8 wfrag8(const float* p){
  const float4* p4 = (const float4*)p;
  float4 a = p4[0], b = p4[1];
  bf16x8 r = { (__bf16)a.x,(__bf16)a.y,(__bf16)a.z,(__bf16)a.w,
               (__bf16)b.x,(__bf16)b.y,(__bf16)b.z,(__bf16)b.w };
  return r;
}
__device__ __forceinline__ void zstore(char* L, int tile, int lane, f32x4 v){
  float* p = (float*)(L + Z_S) + tile*(16*ZROW) + ((lane>>4)*4)*ZROW + (lane&15);
  p[0]=v[0]; p[ZROW]=v[1]; p[2*ZROW]=v[2]; p[3*ZROW]=v[3];
}
__device__ __forceinline__ float zread(const char* L, int tile, int r, int c){
  return ((const float*)(L + Z_S))[tile*(16*ZROW) + r*ZROW + c];
}

// Z tile ids: gate g U-part = g*2+m ; x-part = 8+4*m+g ; decomp = 16+m
__global__ void __launch_bounds__(256, 1) tlstm_scan(ScanP P)
{
  __shared__ __align__(16) char L[LDS_SZ];
  const int tid  = threadIdx.x;
  const int bid  = blockIdx.x;
  const int g    = bid & 7;          // row group
  const int cs   = bid >> 3;         // 0..31
  const int rbase = g * 32;
  const int cbase = cs * 16;
  const int wave = tid >> 6, lane = tid & 63, lo = lane & 15, hi = lane >> 4;

  // ---- one-time: Win slices (4 gates x 16 cols x 256) fp32 -> bf16 -> LDS
  {
    const float* Wg = (tid < 64) ? P.Wi_w : (tid < 128) ? P.Wf_w
                    : (tid < 192) ? P.Wo_w : P.Wc_w;
    int wr = (tid >> 2) & 15, q = tid & 3;
    const float4* src = (const float4*)(Wg + (size_t)(cbase + wr) * DIN + q * 64);
    char* dst = L + WIN_S + (size_t)((tid >> 6) * 16 + wr) * XSTR + q * 128;
#pragma unroll
    for (int j = 0; j < 8; j++){
      float4 a = src[2*j], b = src[2*j+1];
      bf16x8 o = { (__bf16)a.x,(__bf16)a.y,(__bf16)a.z,(__bf16)a.w,
                   (__bf16)b.x,(__bf16)b.y,(__bf16)b.z,(__bf16)b.w };
      *(bf16x8*)(dst + j*16) = o;
    }
  }

  // ---- one-time: U/Wd B-fragments -> registers (loop-invariant)
  bf16x8 bP[16], bQ[16];
  {
    const float* Pw = (wave == 0) ? P.Ui_w : (wave == 1) ? P.Uo_w : P.Wd_w;
#pragma unroll
    for (int kc = 0; kc < 16; kc++)
      bP[kc] = wfrag8(Pw + (size_t)(cbase + lo) * HID + kc * 32 + hi * 8);
    if (wave < 2){
      const float* Qw = (wave == 0) ? P.Uf_w : P.Uc_w;
#pragma unroll
      for (int kc = 0; kc < 16; kc++)
        bQ[kc] = wfrag8(Qw + (size_t)(cbase + lo) * HID + kc * 32 + hi * 8);
    }
  }

  // ---- per-thread elementwise ownership
  const int erow = tid >> 3;
  const int ecp  = (tid & 7) * 2;
  float bias_i[2], bias_f[2], bias_o[2], bias_c[2], bias_d[2], cr[2];
#pragma unroll
  for (int e = 0; e < 2; e++){
    int c = cbase + ecp + e;
    bias_i[e] = P.Wi_b[c] + P.bi[c]  + P.Ui_b[c];
    bias_f[e] = P.Wf_b[c] + P.bf_[c] + P.Uf_b[c];
    bias_o[e] = P.Wo_b[c] + P.bo[c]  + P.Uo_b[c];
    bias_c[e] = P.Wc_b[c] + P.bc[c]  + P.Uc_b[c];
    bias_d[e] = P.b_dec[c];
    cr[e] = 0.f;
  }

  const int srow = tid >> 3, sseg = tid & 7;   // x staging map

#pragma unroll 1
  for (int t = 0; t < T_STEPS; ++t){
    const int rp = t & 1;
    const char* hcprev = (const char*)(P.hc_buf + (size_t)rp * BATCH * 256);
    char* hcnext = (char*)(P.hc_buf + (size_t)(rp ^ 1) * BATCH * 256);

    // x slice + tim (independent of peers): issue early
    const float4* xsrc = (const float4*)(P.x + ((size_t)(rbase + srow) * T_STEPS + t) * DIN + sseg * 32);
    float4 xv[8];
#pragma unroll
    for (int j = 0; j < 8; j++) xv[j] = xsrc[j];
    float tv = P.tim[(size_t)(rbase + erow) * T_STEPS + t];

    __syncthreads();      // old LDS uses finished -> safe to restage

    // ---- issue all h/c coherent loads (16 x dwordx4 per thread, in flight)
    uint4 gr[16];
    const char* src = hcprev + (size_t)(rbase + wave * 8) * 2048;
#pragma unroll
    for (int j = 0; j < 16; j++){
      int row = j >> 1;                       // within this wave's 8 rows
      int gg  = (j & 1) * 64 + lane;          // 16B granule within row
      gr[j] = cld16(src + (size_t)row * 2048 + (size_t)gg * 16);
    }

    // ---- stage x (fp32 -> bf16) — fills the h/c load shadow
    {
      char* dst = L + X_S + srow * XSTR + sseg * 64;
#pragma unroll
      for (int j = 0; j < 4; j++){
        float4 a = xv[2*j], b = xv[2*j+1];
        bf16x8 o = { (__bf16)a.x,(__bf16)a.y,(__bf16)a.z,(__bf16)a.w,
                     (__bf16)b.x,(__bf16)b.y,(__bf16)b.z,(__bf16)b.w };
        *(bf16x8*)(dst + j*16) = o;
      }
    }

    asm volatile("s_waitcnt vmcnt(0)" ::: "memory");
    __builtin_amdgcn_sched_barrier(0);

    // ---- validate tags (every dword carries the full 2-bit tag in bit0 and
    //      bit16); retry until fresh. Guarded: no-hang by construction.
    {
      const unsigned int expv = (unsigned int)(t & 1)
                              | ((unsigned int)((t >> 1) & 1) << 16);
      unsigned int bad = 0;
#pragma unroll
      for (int j = 0; j < 16; j++)
        bad |= ((gr[j].x ^ expv) | (gr[j].y ^ expv)
              | (gr[j].z ^ expv) | (gr[j].w ^ expv)) & 0x00010001u;
      int guard = 0;
      while (__any((int)bad) && ++guard < 65536){
#pragma unroll
        for (int j = 0; j < 16; j++){
          int row = j >> 1;
          int gg  = (j & 1) * 64 + lane;
          gr[j] = cld16(src + (size_t)row * 2048 + (size_t)gg * 16);
        }
        asm volatile("s_waitcnt vmcnt(0)" ::: "memory");
        __builtin_amdgcn_sched_barrier(0);
        bad = 0;
#pragma unroll
        for (int j = 0; j < 16; j++)
          bad |= ((gr[j].x ^ expv) | (gr[j].y ^ expv)
                | (gr[j].z ^ expv) | (gr[j].w ^ expv)) & 0x00010001u;
      }
    }

    // ---- commit h/c to LDS. granule gg covers cols 4gg..4gg+3:
    //      gr = [h01, c01, h23, c23] -> h u64 {x,z}, c u64 {y,w}
    {
#pragma unroll
      for (int j = 0; j < 16; j++){
        int row = wave * 8 + (j >> 1);
        int gg  = (j & 1) * 64 + lane;
        *(uint2*)(L + H_S + row * HSTR + gg * 8) = uint2{gr[j].x, gr[j].z};
        *(uint2*)(L + C_S + row * HSTR + gg * 8) = uint2{gr[j].y, gr[j].w};
      }
    }
    __syncthreads();

    // ---- MFMA phase
    if (wave < 2){
      // wave0: Zi,Zf (U-parts, both M-tiles); wave1: Zo,Zc
      f32x4 z0 = {0.f,0.f,0.f,0.f}, z1 = z0, z2 = z0, z3 = z0;
#pragma unroll
      for (int kc = 0; kc < 16; kc++){
        bf16x8 a0 = *(const bf16x8*)(L + H_S + lo * HSTR        + kc*64 + hi*16);
        bf16x8 a1 = *(const bf16x8*)(L + H_S + (16 + lo) * HSTR + kc*64 + hi*16);
        z0 = MFMA(a0, bP[kc], z0);
        z1 = MFMA(a1, bP[kc], z1);
        z2 = MFMA(a0, bQ[kc], z2);
        z3 = MFMA(a1, bQ[kc], z3);
      }
      int tb = wave * 4;   // tiles {0..3} = Zi m0,m1, Zf m0,m1 ; {4..7} = Zo,Zc
      zstore(L, tb+0, lane, z0); zstore(L, tb+1, lane, z1);
      zstore(L, tb+2, lane, z2); zstore(L, tb+3, lane, z3);
    } else {
      // wave2: x-projections m0 (4 gates) + decomp m0 ; wave3: same for m1
      const int m = wave - 2;
      f32x4 xi = {0.f,0.f,0.f,0.f}, xf = xi, xo = xi, xcg = xi, zd = xi;
#pragma unroll
      for (int q = 0; q < 8; q++){
        bf16x8 a  = *(const bf16x8*)(L + X_S   + (m*16 + lo) * XSTR + q*64 + hi*16);
        bf16x8 w0 = *(const bf16x8*)(L + WIN_S + (0*16 + lo) * XSTR + q*64 + hi*16);
        bf16x8 w1 = *(const bf16x8*)(L + WIN_S + (1*16 + lo) * XSTR + q*64 + hi*16);
        bf16x8 w2 = *(const bf16x8*)(L + WIN_S + (2*16 + lo) * XSTR + q*64 + hi*16);
        bf16x8 w3 = *(const bf16x8*)(L + WIN_S + (3*16 + lo) * XSTR + q*64 + hi*16);
        xi  = MFMA(a, w0, xi);  xf  = MFMA(a, w1, xf);
        xo  = MFMA(a, w2, xo);  xcg = MFMA(a, w3, xcg);
      }
#pragma unroll
      for (int kc = 0; kc < 16; kc++){
        bf16x8 a = *(const bf16x8*)(L + C_S + (m*16 + lo) * HSTR + kc*64 + hi*16);
        zd = MFMA(a, bP[kc], zd);
      }
      zstore(L, 8+4*m+0, lane, xi);  zstore(L, 8+4*m+1, lane, xf);
      zstore(L, 8+4*m+2, lane, xo);  zstore(L, 8+4*m+3, lane, xcg);
      zstore(L, 16+m,    lane, zd);
    }
    __syncthreads();

    // ---- elementwise gate math (fp32); publish tagged u64 (no drain, no flag)
    {
      const int m = erow >> 4, r16 = erow & 15;
      float Tmap = 1.f / __logf(tv + 2.7183f);
      unsigned int hpk = 0, cpk = 0;
      float hv2[2];
#pragma unroll
      for (int e = 0; e < 2; e++){
        int col = ecp + e;
        float zi = zread(L, 0*2+m, r16, col) + zread(L, 8+4*m+0, r16, col) + bias_i[e];
        float zf = zread(L, 1*2+m, r16, col) + zread(L, 8+4*m+1, r16, col) + bias_f[e];
        float zo = zread(L, 2*2+m, r16, col) + zread(L, 8+4*m+2, r16, col) + bias_o[e];
        float zc = zread(L, 3*2+m, r16, col) + zread(L, 8+4*m+3, r16, col) + bias_c[e];
        float zdv = zread(L, 16+m, r16, col) + bias_d[e];
        float cst = ftanh(zdv);
        float c1  = cr[e] - cst + Tmap * cst;
        float ig = fsigm(zi), fg = fsigm(zf), og = fsigm(zo);
        float ch = ftanh(zc);
        float c2 = fg * c1 + ig * ch;
        float hv_ = og * ftanh(c2);
        cr[e] = c2; hv2[e] = hv_;
        hpk |= (unsigned int)__builtin_bit_cast(unsigned short, (__bf16)hv_) << (16*e);
        cpk |= (unsigned int)__builtin_bit_cast(unsigned short, (__bf16)c2) << (16*e);
      }
      if (t < T_STEPS - 1){
        const unsigned int wtag  = (unsigned int)((t + 1) & 3);
        const unsigned int tmask = (wtag & 1u) | ((wtag >> 1) << 16);
        hpk = (hpk & 0xFFFEFFFEu) | tmask;   // full tag in both bf16 LSBs
        cpk = (cpk & 0xFFFEFFFEu) | tmask;
        size_t off = ((size_t)(rbase + erow) * 256 + (cbase >> 1) + (tid & 7)) * 8;
        cst8(hcnext + off,
             (unsigned long long)hpk | ((unsigned long long)cpk << 32));
      } else {
        size_t off = (size_t)(rbase + erow) * HID + cbase + ecp;
        P.h_final[off]     = hv2[0];
        P.h_final[off + 1] = hv2[1];
      }
    }
    __syncthreads();   // keep R3's iteration-tail join (cheap, safe)
  }
}

// ---------------- head: out = relu(hT @ fc_w^T + fc_b) @ cls_w^T + cls_b ----
__global__ void __launch_bounds__(256) tlstm_head(const float* __restrict__ hfin,
    const float* __restrict__ fc_w, const float* __restrict__ fc_b,
    const float* __restrict__ cls_w, const float* __restrict__ cls_b,
    float* __restrict__ out)
{
  __shared__ float hrow[512];
  __shared__ float fcv[256];
  const int b = blockIdx.x, tid = threadIdx.x;
  ((float2*)hrow)[tid] = ((const float2*)(hfin + (size_t)b * 512))[tid];
  __syncthreads();
  {
    const float4* w4 = (const float4*)(fc_w + (size_t)tid * 512);
    const float4* h4 = (const float4*)hrow;
    float acc = fc_b[tid];
#pragma unroll 4
    for (int k = 0; k < 128; k++){
      float4 w = w4[k], h = h4[k];
      acc += w.x*h.x + w.y*h.y + w.z*h.z + w.w*h.w;
    }
    fcv[tid] = fmaxf(acc, 0.f);
  }
  __syncthreads();
  const int wave = tid >> 6, lane = tid & 63;
  if (wave < 2){
    const float* cw = cls_w + wave * 256;
    float s = 0.f;
#pragma unroll
    for (int j = lane; j < 256; j += 64) s += fcv[j] * cw[j];
#pragma unroll
    for (int off = 32; off > 0; off >>= 1) s += __shfl_down(s, off, 64);
    if (lane == 0) out[b * 2 + wave] = s + cls_b[wave];
  }
}

// ---------------------------------------------------------------------------
extern "C" void kernel_launch(void* const* d_in, const int* in_sizes, int n_in,
                              void* d_out, int out_size, void* d_ws, size_t ws_size,
                              hipStream_t stream)
{
  (void)in_sizes; (void)n_in; (void)out_size; (void)ws_size;

  ScanP P;
  P.x    = (const float*)d_in[0];
  P.tim  = (const float*)d_in[1];
  P.Wi_w = (const float*)d_in[2];  P.Wi_b = (const float*)d_in[3];
  P.Ui_w = (const float*)d_in[4];  P.Ui_b = (const float*)d_in[5];  P.bi  = (const float*)d_in[6];
  P.Wf_w = (const float*)d_in[7];  P.Wf_b = (const float*)d_in[8];
  P.Uf_w = (const float*)d_in[9];  P.Uf_b = (const float*)d_in[10]; P.bf_ = (const float*)d_in[11];
  P.Wo_w = (const float*)d_in[12]; P.Wo_b = (const float*)d_in[13];
  P.Uo_w = (const float*)d_in[14]; P.Uo_b = (const float*)d_in[15]; P.bo  = (const float*)d_in[16];
  P.Wc_w = (const float*)d_in[17]; P.Wc_b = (const float*)d_in[18];
  P.Uc_w = (const float*)d_in[19]; P.Uc_b = (const float*)d_in[20]; P.bc  = (const float*)d_in[21];
  P.Wd_w = (const float*)d_in[22]; P.b_dec = (const float*)d_in[23];
  const float* fc_w  = (const float*)d_in[24];
  const float* fc_b  = (const float*)d_in[25];
  const float* cls_w = (const float*)d_in[26];
  const float* cls_b = (const float*)d_in[27];

  // workspace layout (identical to R3): [hc_buf 1M][flags 1K][h_final 512K]
  unsigned long long* hc_buf = (unsigned long long*)d_ws;        // 2*256*256 u64
  unsigned int* flags = (unsigned int*)(hc_buf + 2 * BATCH * 256);
  float* h_final = (float*)((char*)flags + 1024);                // 256*512 f32
  P.hc_buf = hc_buf; P.h_final = h_final; P.flags = flags;

  const size_t zero_bytes = (size_t)2 * BATCH * 256 * 8 + 1024;  // hc + flags
  hipMemsetAsync(d_ws, 0, zero_bytes, stream);

  hipLaunchKernelGGL(tlstm_scan, dim3(256), dim3(256), 0, stream, P);
  hipLaunchKernelGGL(tlstm_head, dim3(256), dim3(256), 0, stream,
                     h_final, fc_w, fc_b, cls_w, cls_b, (float*)d_out);
}